// Round 14
// baseline (185.408 us; speedup 1.0000x reference)
//
#include <hip/hip_runtime.h>
#include <hip/hip_bf16.h>

// dims
#define AB_ELEMS 50331648LL   // 128*24*16384

typedef float f32x4 __attribute__((ext_vector_type(4)));
typedef short short8b __attribute__((ext_vector_type(8)));

__device__ __forceinline__ float gelu_f(float x) {
  return 0.5f * x * (1.0f + erff(x * 0.7071067811865475f));
}

// tanh via exp2: tanh(x) = 1 - 2/(e^{2x}+1); saturation-safe
__device__ __forceinline__ float tanh_f(float x) {
  float e = exp2f(x * 2.8853900817779268f);   // e^(2x)
  float r = __builtin_amdgcn_rcpf(e + 1.f);
  return fmaf(-2.f, r, 1.f);
}

// fp32 -> bf16 bits, RNE
__device__ __forceinline__ unsigned short f2bf(float x) {
  unsigned u = __float_as_uint(x);
  u += 0x7fffu + ((u >> 16) & 1u);
  return (unsigned short)(u >> 16);
}

// block=256 sum; safe for back-to-back calls (leading barrier protects red)
__device__ __forceinline__ float block_sum256(float v, float* red) {
  #pragma unroll
  for (int off = 32; off > 0; off >>= 1) v += __shfl_down(v, off, 64);
  int wid = threadIdx.x >> 6;
  __syncthreads();
  if ((threadIdx.x & 63) == 0) red[wid] = v;
  __syncthreads();
  return red[0] + red[1] + red[2] + red[3];
}

// K1: enc_tok[b,s,m] = gelu(ln(pogt@We + be)); 4 rows per block, thread=m
__global__ __launch_bounds__(256) void k_encoder(
    const float* __restrict__ pogt, const float* __restrict__ We,
    const float* __restrict__ be, const float* __restrict__ lng,
    const float* __restrict__ lnb, float* __restrict__ enc_tok) {
  const int m = threadIdx.x;
  const int row0 = blockIdx.x * 4;
  __shared__ float ps[4][64];
  __shared__ float red[4];
  ps[m >> 6][m & 63] = pogt[row0 * 64 + m];
  __syncthreads();
  float x0 = be[m], x1 = x0, x2 = x0, x3 = x0;
  #pragma unroll 8
  for (int d = 0; d < 64; ++d) {
    float w = We[d * 256 + m];
    x0 = fmaf(ps[0][d], w, x0);
    x1 = fmaf(ps[1][d], w, x1);
    x2 = fmaf(ps[2][d], w, x2);
    x3 = fmaf(ps[3][d], w, x3);
  }
  const float g = lng[m], bb = lnb[m];
  float xs[4] = {x0, x1, x2, x3};
  #pragma unroll
  for (int r = 0; r < 4; ++r) {
    float mu = block_sum256(xs[r], red) * (1.f / 256.f);
    float dv = xs[r] - mu;
    float var = block_sum256(dv * dv, red) * (1.f / 256.f);
    float y = dv * rsqrtf(var + 1e-5f) * g + bb;
    enc_tok[(row0 + r) * 256 + m] = gelu_f(y);
  }
}

// K2: per-batch small chain. encoding -> predictor -> surprise -> gate ->
// mem_new (to d_out) -> hypernet h (bf16, to ws). block=b, thread=m
__global__ __launch_bounds__(256) void k_small(
    const float* __restrict__ enc_tok,
    const float* __restrict__ Wp1, const float* __restrict__ bp1,
    const float* __restrict__ Wp2, const float* __restrict__ bp2,
    const float* __restrict__ bg1, const float* __restrict__ ln_g_g,
    const float* __restrict__ ln_g_b, const float* __restrict__ Wg2,
    const float* __restrict__ bg2, const float* __restrict__ Wh1,
    const float* __restrict__ bh1, const float* __restrict__ ln_h_g,
    const float* __restrict__ ln_h_b, const float* __restrict__ Wh2,
    const float* __restrict__ bh2, float* __restrict__ mem_out,
    unsigned short* __restrict__ hout) {
  const int b = blockIdx.x;
  const int m = threadIdx.x;
  __shared__ float enc_s[256];
  __shared__ float t1_s[256];
  __shared__ float gg_s[256];
  __shared__ float mem_s[256];
  __shared__ float t3_s[128];
  __shared__ float red[4];

  // encoding = mean over S
  float acc = 0.f;
  const float* et = enc_tok + (size_t)b * 64 * 256 + m;
  #pragma unroll 8
  for (int s = 0; s < 64; ++s) acc += et[s * 256];
  const float enc = acc * (1.f / 64.f);
  enc_s[m] = enc;
  __syncthreads();

  // t1 = gelu(enc @ Wp1 + bp1)
  float a0 = 0.f, a1 = 0.f, a2 = 0.f, a3 = 0.f;
  #pragma unroll 4
  for (int d = 0; d < 256; d += 4) {
    a0 = fmaf(enc_s[d + 0], Wp1[(d + 0) * 256 + m], a0);
    a1 = fmaf(enc_s[d + 1], Wp1[(d + 1) * 256 + m], a1);
    a2 = fmaf(enc_s[d + 2], Wp1[(d + 2) * 256 + m], a2);
    a3 = fmaf(enc_s[d + 3], Wp1[(d + 3) * 256 + m], a3);
  }
  t1_s[m] = gelu_f(bp1[m] + ((a0 + a1) + (a2 + a3)));
  __syncthreads();

  // predicted = t1 @ Wp2 + bp2 ; surprise
  a0 = a1 = a2 = a3 = 0.f;
  #pragma unroll 4
  for (int d = 0; d < 256; d += 4) {
    a0 = fmaf(t1_s[d + 0], Wp2[(d + 0) * 256 + m], a0);
    a1 = fmaf(t1_s[d + 1], Wp2[(d + 1) * 256 + m], a1);
    a2 = fmaf(t1_s[d + 2], Wp2[(d + 2) * 256 + m], a2);
    a3 = fmaf(t1_s[d + 3], Wp2[(d + 3) * 256 + m], a3);
  }
  const float pred = bp2[m] + ((a0 + a1) + (a2 + a3));
  const float raw = block_sum256(fabsf(pred - enc), red);
  const float surprise = fminf(fmaxf(raw, 0.f), 1.f);

  // gate (batch-independent: memory==0 so x0 = bg1)
  const float x0 = bg1[m];
  const float mu = block_sum256(x0, red) * (1.f / 256.f);
  const float dv = x0 - mu;
  const float var = block_sum256(dv * dv, red) * (1.f / 256.f);
  gg_s[m] = gelu_f(dv * rsqrtf(var + 1e-5f) * ln_g_g[m] + ln_g_b[m]);
  __syncthreads();
  a0 = a1 = a2 = a3 = 0.f;
  #pragma unroll 4
  for (int d = 0; d < 256; d += 4) {
    a0 = fmaf(gg_s[d + 0], Wg2[(d + 0) * 256 + m], a0);
    a1 = fmaf(gg_s[d + 1], Wg2[(d + 1) * 256 + m], a1);
    a2 = fmaf(gg_s[d + 2], Wg2[(d + 2) * 256 + m], a2);
    a3 = fmaf(gg_s[d + 3], Wg2[(d + 3) * 256 + m], a3);
  }
  const float gx = bg2[m] + ((a0 + a1) + (a2 + a3));
  const float gate = 1.f / (1.f + __expf(-gx));

  // mem_new = clip(gate*surprise*enc, -10, 10)
  float mem = gate * surprise * enc;
  mem = fminf(fmaxf(mem, -10.f), 10.f);
  mem_s[m] = mem;
  mem_out[b * 256 + m] = mem;
  __syncthreads();

  // hypernet: q = mem @ Wh1 + bh1 (128) ; LN ; gelu
  float qv = 0.f;
  if (m < 128) {
    float q0 = 0.f, q1 = 0.f, q2 = 0.f, q3 = 0.f;
    #pragma unroll 4
    for (int d = 0; d < 256; d += 4) {
      q0 = fmaf(mem_s[d + 0], Wh1[(d + 0) * 128 + m], q0);
      q1 = fmaf(mem_s[d + 1], Wh1[(d + 1) * 128 + m], q1);
      q2 = fmaf(mem_s[d + 2], Wh1[(d + 2) * 128 + m], q2);
      q3 = fmaf(mem_s[d + 3], Wh1[(d + 3) * 128 + m], q3);
    }
    qv = bh1[m] + ((q0 + q1) + (q2 + q3));
  }
  const float qmu = block_sum256(m < 128 ? qv : 0.f, red) * (1.f / 128.f);
  const float qd = qv - qmu;
  const float qvar = block_sum256(m < 128 ? qd * qd : 0.f, red) * (1.f / 128.f);
  if (m < 128)
    t3_s[m] = gelu_f(qd * rsqrtf(qvar + 1e-5f) * ln_h_g[m] + ln_h_b[m]);
  __syncthreads();

  // h = gelu(t3 @ Wh2 + bh2) (64) -> bf16
  if (m < 64) {
    float h0 = 0.f, h1 = 0.f;
    #pragma unroll 4
    for (int d = 0; d < 128; d += 2) {
      h0 = fmaf(t3_s[d + 0], Wh2[(d + 0) * 64 + m], h0);
      h1 = fmaf(t3_s[d + 1], Wh2[(d + 1) * 64 + m], h1);
    }
    hout[b * 64 + m] = f2bf(gelu_f(bh2[m] + h0 + h1));
  }
}

// K3 (MFMA): out[b,l,k] = tanh(sum_d h[b,d]*W[l,d,k] + bias[l,k])
// Block tile: 128 b x 256 k (one l, one mat). Wave owns a contiguous 64-k
// slice. W read NON-TEMPORAL (single-use stream, keep caches for the write
// path); epilogue: block LDS transpose -> 1 KB-contiguous NT stores.
__global__ __launch_bounds__(256, 4) void k_lora(
    const float* __restrict__ WA, const float* __restrict__ bA,
    const float* __restrict__ WB, const float* __restrict__ bB,
    const unsigned short* __restrict__ hb, float* __restrict__ out) {
  __shared__ f32x4 xp[32 * 65];         // 33.3 KB: [b_row][k f32x4 0..63 +pad]
  const int t = threadIdx.x;
  const int lane = t & 63;
  const int w = t >> 6;
  const int i = lane & 15;              // A-row (k) / B-col (b) index
  const int g = lane >> 4;              // k-dim group: d = 8g + j
  // XCD-chunked bijective swizzle (3072 = 8 * 384)
  const int orig = blockIdx.x;
  const int bid = (orig & 7) * 384 + (orig >> 3);
  const int kt = bid & 63;              // 64 k-tiles of 256
  const int l = (bid >> 6) % 24;
  const int mat = bid / 1536;           // 0 = A, 1 = B
  const float* __restrict__ W = mat ? WB : WA;
  const float* __restrict__ bias = mat ? bB : bA;
  const int kb = kt * 256 + w * 64;     // wave's k base (64 wide, contiguous)

  const float* Wl = W + (size_t)l * (64 * 16384);

  // A fragments afr[ks][dc]: A[k = kb + ks*16 + i][d = dc*32 + 8g + j]
  // W loads are non-temporal: 201 MB single-use stream, don't cycle caches.
  short8b afr[4][2];
  #pragma unroll
  for (int ks = 0; ks < 4; ++ks) {
    #pragma unroll
    for (int dc = 0; dc < 2; ++dc) {
      const float* p = Wl + (size_t)(dc * 32 + 8 * g) * 16384 + kb + ks * 16 + i;
      #pragma unroll
      for (int j = 0; j < 8; ++j)
        afr[ks][dc][j] = (short)f2bf(__builtin_nontemporal_load(p + (size_t)j * 16384));
    }
  }

  // bias (per-k, broadcast over b)
  f32x4 bv[4];
  #pragma unroll
  for (int ks = 0; ks < 4; ++ks)
    bv[ks] = *(const f32x4*)(bias + (size_t)l * 16384 + kb + ks * 16 + g * 4);

  #pragma unroll
  for (int p = 0; p < 4; ++p) {
    // ---- compute pass p: b in [p*32, p*32+32) ----
    f32x4 acc[4][2];
    #pragma unroll
    for (int ks = 0; ks < 4; ++ks)
      #pragma unroll
      for (int bs = 0; bs < 2; ++bs) acc[ks][bs] = bv[ks];

    #pragma unroll
    for (int bs = 0; bs < 2; ++bs) {
      const unsigned short* hp = hb + (p * 32 + bs * 16 + i) * 64 + 8 * g;
      short8b b0 = *(const short8b*)(hp);        // d = 8g..8g+7
      short8b b1 = *(const short8b*)(hp + 32);   // d = 32 + 8g..
      #pragma unroll
      for (int ks = 0; ks < 4; ++ks) {
        acc[ks][bs] = __builtin_amdgcn_mfma_f32_16x16x32_bf16(afr[ks][0], b0,
                                                              acc[ks][bs], 0, 0, 0);
        acc[ks][bs] = __builtin_amdgcn_mfma_f32_16x16x32_bf16(afr[ks][1], b1,
                                                              acc[ks][bs], 0, 0, 0);
      }
    }

    // ---- epilogue pass p: tanh -> LDS transpose -> 1KB NT stores ----
    __syncthreads();                    // previous pass's reads complete
    // acc reg r of [ks][bs] = (k_local = w*64 + ks*16 + g*4 + r, b = bs*16+i)
    #pragma unroll
    for (int ks = 0; ks < 4; ++ks) {
      #pragma unroll
      for (int bs = 0; bs < 2; ++bs) {
        f32x4 o;
        #pragma unroll
        for (int r = 0; r < 4; ++r) o[r] = tanh_f(acc[ks][bs][r]);
        xp[(bs * 16 + i) * 65 + (w * 16 + ks * 4 + g)] = o;
      }
    }
    __syncthreads();
    // store: wave w owns rows [w*8, w*8+8); each instr = 1 row x 1024 B.
    #pragma unroll
    for (int it = 0; it < 8; ++it) {
      const int row = w * 8 + it;
      f32x4 v = xp[row * 65 + lane];
      const size_t b_glob = (size_t)(p * 32 + row);
      float* op = out + (size_t)mat * AB_ELEMS + b_glob * (24 * 16384) +
                  (size_t)l * 16384 + kt * 256 + lane * 4;
      __builtin_nontemporal_store(v, (f32x4*)op);
    }
  }
}

extern "C" void kernel_launch(void* const* d_in, const int* in_sizes, int n_in,
                              void* d_out, int out_size, void* d_ws, size_t ws_size,
                              hipStream_t stream) {
  const float* pogt   = (const float*)d_in[0];
  const float* We     = (const float*)d_in[1];
  const float* be     = (const float*)d_in[2];
  const float* ln_e_g = (const float*)d_in[3];
  const float* ln_e_b = (const float*)d_in[4];
  const float* Wp1    = (const float*)d_in[5];
  const float* bp1    = (const float*)d_in[6];
  const float* Wp2    = (const float*)d_in[7];
  const float* bp2    = (const float*)d_in[8];
  // d_in[9] = Wg1 — unused (memory == 0 so memory@Wg1 == 0)
  const float* bg1    = (const float*)d_in[10];
  const float* ln_g_g = (const float*)d_in[11];
  const float* ln_g_b = (const float*)d_in[12];
  const float* Wg2    = (const float*)d_in[13];
  const float* bg2    = (const float*)d_in[14];
  const float* Wh1    = (const float*)d_in[15];
  const float* bh1    = (const float*)d_in[16];
  const float* ln_h_g = (const float*)d_in[17];
  const float* ln_h_b = (const float*)d_in[18];
  const float* Wh2    = (const float*)d_in[19];
  const float* bh2    = (const float*)d_in[20];
  const float* WA     = (const float*)d_in[21];
  const float* bA     = (const float*)d_in[22];
  const float* WB     = (const float*)d_in[23];
  const float* bB     = (const float*)d_in[24];

  float* out = (float*)d_out;
  float* enc_tok = (float*)d_ws;                            // 8 MB
  unsigned short* hbuf = (unsigned short*)((char*)d_ws + 8388608);  // 16 KB bf16
  float* mem_out = out + 2 * AB_ELEMS;                      // [128,256] tail of d_out

  k_encoder<<<2048, 256, 0, stream>>>(pogt, We, be, ln_e_g, ln_e_b, enc_tok);
  k_small<<<128, 256, 0, stream>>>(enc_tok, Wp1, bp1, Wp2, bp2, bg1, ln_g_g,
                                   ln_g_b, Wg2, bg2, Wh1, bh1, ln_h_g, ln_h_b,
                                   Wh2, bh2, mem_out, hbuf);
  k_lora<<<3072, 256, 0, stream>>>(WA, bA, WB, bB, hbuf, out);
}

// Round 15
// 146.638 us; speedup vs baseline: 1.2644x; 1.2644x over previous
//
#include <hip/hip_runtime.h>
#include <hip/hip_bf16.h>

// dims
#define AB_ELEMS 50331648LL   // 128*24*16384

typedef float f32x4 __attribute__((ext_vector_type(4)));
typedef short short8b __attribute__((ext_vector_type(8)));

__device__ __forceinline__ float gelu_f(float x) {
  return 0.5f * x * (1.0f + erff(x * 0.7071067811865475f));
}

// tanh via exp2: tanh(x) = 1 - 2/(e^{2x}+1); saturation-safe
__device__ __forceinline__ float tanh_f(float x) {
  float e = exp2f(x * 2.8853900817779268f);   // e^(2x)
  float r = __builtin_amdgcn_rcpf(e + 1.f);
  return fmaf(-2.f, r, 1.f);
}

// fp32 -> bf16 bits, RNE
__device__ __forceinline__ unsigned short f2bf(float x) {
  unsigned u = __float_as_uint(x);
  u += 0x7fffu + ((u >> 16) & 1u);
  return (unsigned short)(u >> 16);
}

// block=256 sum; safe for back-to-back calls (leading barrier protects red)
__device__ __forceinline__ float block_sum256(float v, float* red) {
  #pragma unroll
  for (int off = 32; off > 0; off >>= 1) v += __shfl_down(v, off, 64);
  int wid = threadIdx.x >> 6;
  __syncthreads();
  if ((threadIdx.x & 63) == 0) red[wid] = v;
  __syncthreads();
  return red[0] + red[1] + red[2] + red[3];
}

// K1: enc_tok[b,s,m] = gelu(ln(pogt@We + be)); 4 rows per block, thread=m
__global__ __launch_bounds__(256) void k_encoder(
    const float* __restrict__ pogt, const float* __restrict__ We,
    const float* __restrict__ be, const float* __restrict__ lng,
    const float* __restrict__ lnb, float* __restrict__ enc_tok) {
  const int m = threadIdx.x;
  const int row0 = blockIdx.x * 4;
  __shared__ float ps[4][64];
  __shared__ float red[4];
  ps[m >> 6][m & 63] = pogt[row0 * 64 + m];
  __syncthreads();
  float x0 = be[m], x1 = x0, x2 = x0, x3 = x0;
  #pragma unroll 8
  for (int d = 0; d < 64; ++d) {
    float w = We[d * 256 + m];
    x0 = fmaf(ps[0][d], w, x0);
    x1 = fmaf(ps[1][d], w, x1);
    x2 = fmaf(ps[2][d], w, x2);
    x3 = fmaf(ps[3][d], w, x3);
  }
  const float g = lng[m], bb = lnb[m];
  float xs[4] = {x0, x1, x2, x3};
  #pragma unroll
  for (int r = 0; r < 4; ++r) {
    float mu = block_sum256(xs[r], red) * (1.f / 256.f);
    float dv = xs[r] - mu;
    float var = block_sum256(dv * dv, red) * (1.f / 256.f);
    float y = dv * rsqrtf(var + 1e-5f) * g + bb;
    enc_tok[(row0 + r) * 256 + m] = gelu_f(y);
  }
}

// K2: per-batch small chain. encoding -> predictor -> surprise -> gate ->
// mem_new (to d_out) -> hypernet h (bf16, to ws). block=b, thread=m
__global__ __launch_bounds__(256) void k_small(
    const float* __restrict__ enc_tok,
    const float* __restrict__ Wp1, const float* __restrict__ bp1,
    const float* __restrict__ Wp2, const float* __restrict__ bp2,
    const float* __restrict__ bg1, const float* __restrict__ ln_g_g,
    const float* __restrict__ ln_g_b, const float* __restrict__ Wg2,
    const float* __restrict__ bg2, const float* __restrict__ Wh1,
    const float* __restrict__ bh1, const float* __restrict__ ln_h_g,
    const float* __restrict__ ln_h_b, const float* __restrict__ Wh2,
    const float* __restrict__ bh2, float* __restrict__ mem_out,
    unsigned short* __restrict__ hout) {
  const int b = blockIdx.x;
  const int m = threadIdx.x;
  __shared__ float enc_s[256];
  __shared__ float t1_s[256];
  __shared__ float gg_s[256];
  __shared__ float mem_s[256];
  __shared__ float t3_s[128];
  __shared__ float red[4];

  // encoding = mean over S
  float acc = 0.f;
  const float* et = enc_tok + (size_t)b * 64 * 256 + m;
  #pragma unroll 8
  for (int s = 0; s < 64; ++s) acc += et[s * 256];
  const float enc = acc * (1.f / 64.f);
  enc_s[m] = enc;
  __syncthreads();

  // t1 = gelu(enc @ Wp1 + bp1)
  float a0 = 0.f, a1 = 0.f, a2 = 0.f, a3 = 0.f;
  #pragma unroll 4
  for (int d = 0; d < 256; d += 4) {
    a0 = fmaf(enc_s[d + 0], Wp1[(d + 0) * 256 + m], a0);
    a1 = fmaf(enc_s[d + 1], Wp1[(d + 1) * 256 + m], a1);
    a2 = fmaf(enc_s[d + 2], Wp1[(d + 2) * 256 + m], a2);
    a3 = fmaf(enc_s[d + 3], Wp1[(d + 3) * 256 + m], a3);
  }
  t1_s[m] = gelu_f(bp1[m] + ((a0 + a1) + (a2 + a3)));
  __syncthreads();

  // predicted = t1 @ Wp2 + bp2 ; surprise
  a0 = a1 = a2 = a3 = 0.f;
  #pragma unroll 4
  for (int d = 0; d < 256; d += 4) {
    a0 = fmaf(t1_s[d + 0], Wp2[(d + 0) * 256 + m], a0);
    a1 = fmaf(t1_s[d + 1], Wp2[(d + 1) * 256 + m], a1);
    a2 = fmaf(t1_s[d + 2], Wp2[(d + 2) * 256 + m], a2);
    a3 = fmaf(t1_s[d + 3], Wp2[(d + 3) * 256 + m], a3);
  }
  const float pred = bp2[m] + ((a0 + a1) + (a2 + a3));
  const float raw = block_sum256(fabsf(pred - enc), red);
  const float surprise = fminf(fmaxf(raw, 0.f), 1.f);

  // gate (batch-independent: memory==0 so x0 = bg1)
  const float x0 = bg1[m];
  const float mu = block_sum256(x0, red) * (1.f / 256.f);
  const float dv = x0 - mu;
  const float var = block_sum256(dv * dv, red) * (1.f / 256.f);
  gg_s[m] = gelu_f(dv * rsqrtf(var + 1e-5f) * ln_g_g[m] + ln_g_b[m]);
  __syncthreads();
  a0 = a1 = a2 = a3 = 0.f;
  #pragma unroll 4
  for (int d = 0; d < 256; d += 4) {
    a0 = fmaf(gg_s[d + 0], Wg2[(d + 0) * 256 + m], a0);
    a1 = fmaf(gg_s[d + 1], Wg2[(d + 1) * 256 + m], a1);
    a2 = fmaf(gg_s[d + 2], Wg2[(d + 2) * 256 + m], a2);
    a3 = fmaf(gg_s[d + 3], Wg2[(d + 3) * 256 + m], a3);
  }
  const float gx = bg2[m] + ((a0 + a1) + (a2 + a3));
  const float gate = 1.f / (1.f + __expf(-gx));

  // mem_new = clip(gate*surprise*enc, -10, 10)
  float mem = gate * surprise * enc;
  mem = fminf(fmaxf(mem, -10.f), 10.f);
  mem_s[m] = mem;
  mem_out[b * 256 + m] = mem;
  __syncthreads();

  // hypernet: q = mem @ Wh1 + bh1 (128) ; LN ; gelu
  float qv = 0.f;
  if (m < 128) {
    float q0 = 0.f, q1 = 0.f, q2 = 0.f, q3 = 0.f;
    #pragma unroll 4
    for (int d = 0; d < 256; d += 4) {
      q0 = fmaf(mem_s[d + 0], Wh1[(d + 0) * 128 + m], q0);
      q1 = fmaf(mem_s[d + 1], Wh1[(d + 1) * 128 + m], q1);
      q2 = fmaf(mem_s[d + 2], Wh1[(d + 2) * 128 + m], q2);
      q3 = fmaf(mem_s[d + 3], Wh1[(d + 3) * 128 + m], q3);
    }
    qv = bh1[m] + ((q0 + q1) + (q2 + q3));
  }
  const float qmu = block_sum256(m < 128 ? qv : 0.f, red) * (1.f / 128.f);
  const float qd = qv - qmu;
  const float qvar = block_sum256(m < 128 ? qd * qd : 0.f, red) * (1.f / 128.f);
  if (m < 128)
    t3_s[m] = gelu_f(qd * rsqrtf(qvar + 1e-5f) * ln_h_g[m] + ln_h_b[m]);
  __syncthreads();

  // h = gelu(t3 @ Wh2 + bh2) (64) -> bf16
  if (m < 64) {
    float h0 = 0.f, h1 = 0.f;
    #pragma unroll 4
    for (int d = 0; d < 128; d += 2) {
      h0 = fmaf(t3_s[d + 0], Wh2[(d + 0) * 64 + m], h0);
      h1 = fmaf(t3_s[d + 1], Wh2[(d + 1) * 64 + m], h1);
    }
    hout[b * 64 + m] = f2bf(gelu_f(bh2[m] + h0 + h1));
  }
}

// K3 (MFMA): out[b,l,k] = tanh(sum_d h[b,d]*W[l,d,k] + bias[l,k])
// Block tile: 128 b x 256 k (one l, one mat). Wave owns a contiguous 64-k
// slice. Cached W loads (L3 serves ~half across replays; NT loads measured
// +38us) + NT stores (plain stores measured +62us). Block LDS transpose ->
// 1 KB-contiguous stores. XCD-chunked bijective swizzle.
__global__ __launch_bounds__(256, 4) void k_lora(
    const float* __restrict__ WA, const float* __restrict__ bA,
    const float* __restrict__ WB, const float* __restrict__ bB,
    const unsigned short* __restrict__ hb, float* __restrict__ out) {
  __shared__ f32x4 xp[32 * 65];         // 33.3 KB: [b_row][k f32x4 0..63 +pad]
  const int t = threadIdx.x;
  const int lane = t & 63;
  const int w = t >> 6;
  const int i = lane & 15;              // A-row (k) / B-col (b) index
  const int g = lane >> 4;              // k-dim group: d = 8g + j
  // XCD-chunked bijective swizzle (3072 = 8 * 384)
  const int orig = blockIdx.x;
  const int bid = (orig & 7) * 384 + (orig >> 3);
  const int kt = bid & 63;              // 64 k-tiles of 256
  const int l = (bid >> 6) % 24;
  const int mat = bid / 1536;           // 0 = A, 1 = B
  const float* __restrict__ W = mat ? WB : WA;
  const float* __restrict__ bias = mat ? bB : bA;
  const int kb = kt * 256 + w * 64;     // wave's k base (64 wide, contiguous)

  const float* Wl = W + (size_t)l * (64 * 16384);

  // A fragments afr[ks][dc]: A[k = kb + ks*16 + i][d = dc*32 + 8g + j]
  short8b afr[4][2];
  #pragma unroll
  for (int ks = 0; ks < 4; ++ks) {
    #pragma unroll
    for (int dc = 0; dc < 2; ++dc) {
      const float* p = Wl + (size_t)(dc * 32 + 8 * g) * 16384 + kb + ks * 16 + i;
      #pragma unroll
      for (int j = 0; j < 8; ++j)
        afr[ks][dc][j] = (short)f2bf(p[(size_t)j * 16384]);
    }
  }

  // bias (per-k, broadcast over b)
  f32x4 bv[4];
  #pragma unroll
  for (int ks = 0; ks < 4; ++ks)
    bv[ks] = *(const f32x4*)(bias + (size_t)l * 16384 + kb + ks * 16 + g * 4);

  #pragma unroll
  for (int p = 0; p < 4; ++p) {
    // ---- compute pass p: b in [p*32, p*32+32) ----
    f32x4 acc[4][2];
    #pragma unroll
    for (int ks = 0; ks < 4; ++ks)
      #pragma unroll
      for (int bs = 0; bs < 2; ++bs) acc[ks][bs] = bv[ks];

    #pragma unroll
    for (int bs = 0; bs < 2; ++bs) {
      const unsigned short* hp = hb + (p * 32 + bs * 16 + i) * 64 + 8 * g;
      short8b b0 = *(const short8b*)(hp);        // d = 8g..8g+7
      short8b b1 = *(const short8b*)(hp + 32);   // d = 32 + 8g..
      #pragma unroll
      for (int ks = 0; ks < 4; ++ks) {
        acc[ks][bs] = __builtin_amdgcn_mfma_f32_16x16x32_bf16(afr[ks][0], b0,
                                                              acc[ks][bs], 0, 0, 0);
        acc[ks][bs] = __builtin_amdgcn_mfma_f32_16x16x32_bf16(afr[ks][1], b1,
                                                              acc[ks][bs], 0, 0, 0);
      }
    }

    // ---- epilogue pass p: tanh -> LDS transpose -> 1KB NT stores ----
    __syncthreads();                    // previous pass's reads complete
    // acc reg r of [ks][bs] = (k_local = w*64 + ks*16 + g*4 + r, b = bs*16+i)
    #pragma unroll
    for (int ks = 0; ks < 4; ++ks) {
      #pragma unroll
      for (int bs = 0; bs < 2; ++bs) {
        f32x4 o;
        #pragma unroll
        for (int r = 0; r < 4; ++r) o[r] = tanh_f(acc[ks][bs][r]);
        xp[(bs * 16 + i) * 65 + (w * 16 + ks * 4 + g)] = o;
      }
    }
    __syncthreads();
    // store: wave w owns rows [w*8, w*8+8); each instr = 1 row x 1024 B.
    #pragma unroll
    for (int it = 0; it < 8; ++it) {
      const int row = w * 8 + it;
      f32x4 v = xp[row * 65 + lane];
      const size_t b_glob = (size_t)(p * 32 + row);
      float* op = out + (size_t)mat * AB_ELEMS + b_glob * (24 * 16384) +
                  (size_t)l * 16384 + kt * 256 + lane * 4;
      __builtin_nontemporal_store(v, (f32x4*)op);
    }
  }
}

extern "C" void kernel_launch(void* const* d_in, const int* in_sizes, int n_in,
                              void* d_out, int out_size, void* d_ws, size_t ws_size,
                              hipStream_t stream) {
  const float* pogt   = (const float*)d_in[0];
  const float* We     = (const float*)d_in[1];
  const float* be     = (const float*)d_in[2];
  const float* ln_e_g = (const float*)d_in[3];
  const float* ln_e_b = (const float*)d_in[4];
  const float* Wp1    = (const float*)d_in[5];
  const float* bp1    = (const float*)d_in[6];
  const float* Wp2    = (const float*)d_in[7];
  const float* bp2    = (const float*)d_in[8];
  // d_in[9] = Wg1 — unused (memory == 0 so memory@Wg1 == 0)
  const float* bg1    = (const float*)d_in[10];
  const float* ln_g_g = (const float*)d_in[11];
  const float* ln_g_b = (const float*)d_in[12];
  const float* Wg2    = (const float*)d_in[13];
  const float* bg2    = (const float*)d_in[14];
  const float* Wh1    = (const float*)d_in[15];
  const float* bh1    = (const float*)d_in[16];
  const float* ln_h_g = (const float*)d_in[17];
  const float* ln_h_b = (const float*)d_in[18];
  const float* Wh2    = (const float*)d_in[19];
  const float* bh2    = (const float*)d_in[20];
  const float* WA     = (const float*)d_in[21];
  const float* bA     = (const float*)d_in[22];
  const float* WB     = (const float*)d_in[23];
  const float* bB     = (const float*)d_in[24];

  float* out = (float*)d_out;
  float* enc_tok = (float*)d_ws;                            // 8 MB
  unsigned short* hbuf = (unsigned short*)((char*)d_ws + 8388608);  // 16 KB bf16
  float* mem_out = out + 2 * AB_ELEMS;                      // [128,256] tail of d_out

  k_encoder<<<2048, 256, 0, stream>>>(pogt, We, be, ln_e_g, ln_e_b, enc_tok);
  k_small<<<128, 256, 0, stream>>>(enc_tok, Wp1, bp1, Wp2, bp2, bg1, ln_g_g,
                                   ln_g_b, Wg2, bg2, Wh1, bh1, ln_h_g, ln_h_b,
                                   Wh2, bh2, mem_out, hbuf);
  k_lora<<<3072, 256, 0, stream>>>(WA, bA, WB, bB, hbuf, out);
}